// Round 13
// baseline (60.113 us; speedup 1.0000x reference)
//
#include <hip/hip_runtime.h>

#define TOTAL     4194304
#define DIM       32
#define NTOK      (TOTAL / DIM)   // 131072 tokens
#define NCODE     1024
#define CCODES    256             // codes per chunk (4 chunks) -- proven R5 geometry
#define DELTA_EPS 2e-3f
#define FLAGBIT   0x40000000

typedef _Float16 half8   __attribute__((ext_vector_type(8)));
typedef float    floatx4 __attribute__((ext_vector_type(4)));

#define GLOAD_LDS16(g, l) \
    __builtin_amdgcn_global_load_lds((const __attribute__((address_space(1))) void*)(g), \
                                     (__attribute__((address_space(3))) void*)(l), 16, 0, 0)
#define GLOAD_LDS4(g, l) \
    __builtin_amdgcn_global_load_lds((const __attribute__((address_space(1))) void*)(g), \
                                     (__attribute__((address_space(3))) void*)(l), 4, 0, 0)

// ---------------- prep: codebook -> f16 hi/lo split in FRAGMENT ORDER + (-0.5*|e|^2) ----
// Fragment slot for code k (256-code chunks): chunk=k>>8, step=(k&255)>>4, l15=k&15;
// slot = chunk*1024 + step*64 + l4*16 + l15 (8 halves = 16 B per slot).
__global__ __launch_bounds__(64) void vq_prep(
    const float* __restrict__ cb, float* __restrict__ nhb,
    _Float16* __restrict__ Eh, _Float16* __restrict__ El)
{
    const int k = blockIdx.x * 64 + threadIdx.x;   // code id
    const float4* e4 = reinterpret_cast<const float4*>(cb) + (size_t)k * 8;
    float v[DIM];
    float4 t[8];
#pragma unroll
    for (int j = 0; j < 8; ++j) t[j] = e4[j];
#pragma unroll
    for (int j = 0; j < 8; ++j) {
        v[4 * j + 0] = t[j].x; v[4 * j + 1] = t[j].y;
        v[4 * j + 2] = t[j].z; v[4 * j + 3] = t[j].w;
    }
    float e2 = 0.0f;
#pragma unroll
    for (int i = 0; i < DIM; ++i) e2 = fmaf(v[i], v[i], e2);   // sequential: matches rescore
    nhb[k] = -0.5f * e2;

    const int chunk = k >> 8, within = k & 255;
    const int step = within >> 4, l15 = within & 15;
#pragma unroll
    for (int l4 = 0; l4 < 4; ++l4) {
        half8 h, lo;
#pragma unroll
        for (int j = 0; j < 8; ++j) {
            float x = v[l4 * 8 + j];
            _Float16 hh = (_Float16)x;
            h[j]  = hh;
            lo[j] = (_Float16)(x - (float)hh);
        }
        const int slot = chunk * 1024 + step * 64 + l4 * 16 + l15;
        *reinterpret_cast<half8*>(Eh + (size_t)slot * 8) = h;
        *reinterpret_cast<half8*>(El + (size_t)slot * 8) = lo;
    }
}

// ---------------- main: R5-proven MFMA argmax (6-bit payload) + fused exact rescore ----
// 1024 blocks x 256 thr; wave owns 32 tokens (m=2); 4 chunks x 256 codes; LDS 33.5 KB.
// Score payload = 6 step bits only (granule 16x finer than R12); the 4 code-lane bits
// are recovered positionally in the lane-explicit xor-reduce.
__global__ __launch_bounds__(256) void vq_main(
    const float* __restrict__ w, const float* __restrict__ c,
    const float* __restrict__ nhb, const _Float16* __restrict__ Eh,
    const _Float16* __restrict__ El, const float* __restrict__ cb,
    int* __restrict__ out)
{
    __shared__ _Float16 sEh[1024 * 8];   // 16 KB: [step(16)][lane(64)][8 halves]
    __shared__ _Float16 sEl[1024 * 8];   // 16 KB
    __shared__ float    snh[CCODES];     // 1 KB
    __shared__ int      sOut[128];       // 512 B

    const int tid  = threadIdx.x;
    const int lane = tid & 63;
    const int wid  = tid >> 6;
    const int tokw = blockIdx.x * 128 + wid * 32;   // 32 tokens per wave
    const int l15  = lane & 15;
    const int l4   = lane >> 4;

    // A fragments: 2 tiles of 16 tokens. A[row=l15][k=l4*8+j]; exact x = xh + xl
    half8 xh[2], xl[2];
#pragma unroll
    for (int m = 0; m < 2; ++m) {
        const int token = tokw + m * 16 + l15;
        const float4* pw = reinterpret_cast<const float4*>(w + (size_t)token * DIM + l4 * 8);
        const float4* pc = reinterpret_cast<const float4*>(c + (size_t)token * DIM + l4 * 8);
        float4 a0 = pw[0], a1 = pw[1], b0 = pc[0], b1 = pc[1];
        float xs[8] = {a0.x - b0.x, a0.y - b0.y, a0.z - b0.z, a0.w - b0.w,
                       a1.x - b1.x, a1.y - b1.y, a1.z - b1.z, a1.w - b1.w};
#pragma unroll
        for (int j = 0; j < 8; ++j) {
            _Float16 h = (_Float16)xs[j];
            xh[m][j] = h;
            xl[m][j] = (_Float16)(xs[j] - (float)h);
        }
    }

    const float NEGINF = __uint_as_float(0xFF800000u);
    float best[8], second[8];
#pragma unroll
    for (int q = 0; q < 8; ++q) { best[q] = NEGINF; second[q] = NEGINF; }

    for (int ch = 0; ch < 4; ++ch) {
        if (ch) __syncthreads();   // all waves done reading previous chunk before overwrite
        {   // stage 256 codes (hi+lo, 32 KB) + snh (1 KB), all-linear async global->LDS
            const _Float16* gh = Eh + (size_t)ch * 8192;
            const _Float16* gl = El + (size_t)ch * 8192;
#pragma unroll
            for (int r2 = 0; r2 < 4; ++r2) {
                const int slot = r2 * 256 + wid * 64;   // wave-uniform base
                GLOAD_LDS16(gh + (size_t)(slot + lane) * 8, sEh + (size_t)slot * 8);
                GLOAD_LDS16(gl + (size_t)(slot + lane) * 8, sEl + (size_t)slot * 8);
            }
            GLOAD_LDS4(nhb + ch * CCODES + wid * 64 + lane, snh + wid * 64);
        }
        __syncthreads();   // drain -> staged data visible

        // 16 steps of 16 codes, in pairs (med3 second-tracking) -- R5's proven loop
#pragma unroll
        for (int sp = 0; sp < 8; ++sp) {
            const int sA = 2 * sp, sB = 2 * sp + 1;
            const half8 ehA = *reinterpret_cast<const half8*>(sEh + (size_t)(sA * 64 + lane) * 8);
            const half8 elA = *reinterpret_cast<const half8*>(sEl + (size_t)(sA * 64 + lane) * 8);
            const half8 ehB = *reinterpret_cast<const half8*>(sEh + (size_t)(sB * 64 + lane) * 8);
            const half8 elB = *reinterpret_cast<const half8*>(sEl + (size_t)(sB * 64 + lane) * 8);
            const float nhA = snh[sA * 16 + l15];
            const float nhB = snh[sB * 16 + l15];
            // 6-bit payload: global step id only (63 - gstep), lane bits carried positionally
            const unsigned ixA = 63u - (unsigned)(ch * 16 + sA);
            const unsigned ixB = ixA - 1u;
            const floatx4 nA = {nhA, nhA, nhA, nhA};
            const floatx4 nB = {nhB, nhB, nhB, nhB};
#pragma unroll
            for (int m = 0; m < 2; ++m) {
                floatx4 aA = __builtin_amdgcn_mfma_f32_16x16x32_f16(xh[m], ehA, nA, 0, 0, 0);
                aA = __builtin_amdgcn_mfma_f32_16x16x32_f16(xl[m], ehA, aA, 0, 0, 0);
                aA = __builtin_amdgcn_mfma_f32_16x16x32_f16(xh[m], elA, aA, 0, 0, 0);
                floatx4 aB = __builtin_amdgcn_mfma_f32_16x16x32_f16(xh[m], ehB, nB, 0, 0, 0);
                aB = __builtin_amdgcn_mfma_f32_16x16x32_f16(xl[m], ehB, aB, 0, 0, 0);
                aB = __builtin_amdgcn_mfma_f32_16x16x32_f16(xh[m], elB, aB, 0, 0, 0);
#pragma unroll
                for (int r = 0; r < 4; ++r) {
                    const int q = m * 4 + r;
                    float pA = __uint_as_float((__float_as_uint(aA[r]) & 0xFFFFFFC0u) | ixA);
                    float pB = __uint_as_float((__float_as_uint(aB[r]) & 0xFFFFFFC0u) | ixB);
                    second[q] = fmaxf(second[q], __builtin_amdgcn_fmed3f(pA, pB, best[q]));
                    best[q]   = fmaxf(fmaxf(best[q], pA), pB);
                }
            }
        }
    }

    // reduce across the 16 code-lanes, tracking the winning lane explicitly
    int lidx[8];
#pragma unroll
    for (int q = 0; q < 8; ++q) lidx[q] = l15;
#pragma unroll
    for (int sh = 1; sh < 16; sh <<= 1) {
#pragma unroll
        for (int q = 0; q < 8; ++q) {
            float bB = __shfl_xor(best[q], sh);
            float sB = __shfl_xor(second[q], sh);
            int   lB = __shfl_xor(lidx[q], sh);
            second[q] = fmaxf(fmaxf(second[q], sB), fminf(best[q], bB));
            bool take = (bB > best[q]) || (bB == best[q] && lB < lidx[q]);
            best[q] = take ? bB : best[q];
            lidx[q] = take ? lB : lidx[q];
        }
    }

    // stage per-token results (k | optional FLAGBIT); fine 6-bit granule threshold
    if (l15 == 0) {
#pragma unroll
        for (int m = 0; m < 2; ++m) {
#pragma unroll
            for (int r = 0; r < 4; ++r) {
                const int q = m * 4 + r;
                unsigned ub = __float_as_uint(best[q]);
                unsigned us = __float_as_uint(second[q]);
                float bv = __uint_as_float(ub & 0xFFFFFFC0u);
                float sv = __uint_as_float(us & 0xFFFFFFC0u);
                int eb = (int)((ub >> 23) & 255u);
                int es = (int)((us >> 23) & 255u);
                int em = eb > es ? eb : es;
                em = em > 16 ? em : 16;
                // flag threshold = 4 * packing granule (2^(em-127-17)) + eps
                float thr = __uint_as_float((unsigned)(em - 15) << 23) + DELTA_EPS;
                int gstep = 63 - (int)(ub & 63u);
                int k = gstep * 16 + lidx[q];
                sOut[wid * 32 + m * 16 + l4 * 4 + r] = ((bv - sv) < thr) ? (k | FLAGBIT) : k;
            }
        }
    }

    // lane i (<32) owns token tokw+i; rescore flagged tokens exactly (wave-cooperative).
    int myval = 0;
    if (lane < 32) myval = sOut[wid * 32 + lane];
    unsigned long long mask = __ballot(lane < 32 && (myval & FLAGBIT));
    while (mask) {
        const int src = __ffsll(mask) - 1;
        mask &= mask - 1;
        const int token = tokw + src;   // wave-uniform

        float x[DIM];
#pragma unroll
        for (int j = 0; j < 8; ++j) {
            float4 aw = reinterpret_cast<const float4*>(w + (size_t)token * DIM)[j];
            float4 ac = reinterpret_cast<const float4*>(c + (size_t)token * DIM)[j];
            x[4 * j + 0] = aw.x - ac.x; x[4 * j + 1] = aw.y - ac.y;
            x[4 * j + 2] = aw.z - ac.z; x[4 * j + 3] = aw.w - ac.w;
        }
        float x2 = 0.f;
#pragma unroll
        for (int i = 0; i < DIM; ++i) x2 = fmaf(x[i], x[i], x2);

        float dmin = INFINITY;
        int   kbest = 0;
#pragma unroll 2
        for (int i = 0; i < 16; ++i) {
            const int k = lane + 64 * i;           // ascending per lane
            const float4* e4 = reinterpret_cast<const float4*>(cb) + (size_t)k * 8;
            float4 ev[8];
#pragma unroll
            for (int j = 0; j < 8; ++j) ev[j] = e4[j];
            float dot = 0.f;
#pragma unroll
            for (int j = 0; j < 8; ++j) {          // sequential order: j*4+0..3
                dot = fmaf(x[4 * j + 0], ev[j].x, dot);
                dot = fmaf(x[4 * j + 1], ev[j].y, dot);
                dot = fmaf(x[4 * j + 2], ev[j].z, dot);
                dot = fmaf(x[4 * j + 3], ev[j].w, dot);
            }
            float e2 = -2.0f * nhb[k];             // bit-exact |e|^2 (seq-fma in prep)
            float dd = fmaf(-2.0f, dot, x2) + e2;
            if (dd < dmin) { dmin = dd; kbest = k; }
        }
#pragma unroll
        for (int sh = 1; sh < 64; sh <<= 1) {
            float dB = __shfl_xor(dmin, sh);
            int   iB = __shfl_xor(kbest, sh);
            bool take = (dB < dmin) || (dB == dmin && iB < kbest);
            dmin = take ? dB : dmin;
            kbest = take ? iB : kbest;
        }
        if (lane == src) myval = kbest;   // exact index, flag cleared
    }
    if (lane < 32) out[tokw + lane] = myval;   // coalesced 128 B per wave
}

extern "C" void kernel_launch(void* const* d_in, const int* in_sizes, int n_in,
                              void* d_out, int out_size, void* d_ws, size_t ws_size,
                              hipStream_t stream) {
    const float* w  = (const float*)d_in[0];   // weights   [4194304]
    const float* c  = (const float*)d_in[1];   // condition [1,32,131072] flat
    const float* cb = (const float*)d_in[2];   // codebook  [1024,32]
    int* out = (int*)d_out;                    // int32 indices [131072]

    char* wsb = (char*)d_ws;
    float*    nhb = (float*)wsb;                       // 4 KB
    _Float16* Eh  = (_Float16*)(wsb + 4096);           // 64 KB (fragment-ordered)
    _Float16* El  = (_Float16*)(wsb + 4096 + 65536);   // 64 KB (fragment-ordered)

    vq_prep<<<NCODE / 64, 64, 0, stream>>>(cb, nhb, Eh, El);
    vq_main<<<NTOK / 128, 256, 0, stream>>>(w, c, nhb, Eh, El, cb, out);
}

// Round 14
// 53.008 us; speedup vs baseline: 1.1340x; 1.1340x over previous
//
#include <hip/hip_runtime.h>

#define TOTAL     4194304
#define DIM       32
#define NTOK      (TOTAL / DIM)   // 131072 tokens
#define NCODE     1024
#define DELTA_EPS 2e-3f
#define FLAGBIT   0x40000000

typedef _Float16 half8   __attribute__((ext_vector_type(8)));
typedef float    floatx4 __attribute__((ext_vector_type(4)));

#define GLOAD_LDS16(g, l) \
    __builtin_amdgcn_global_load_lds((const __attribute__((address_space(1))) void*)(g), \
                                     (__attribute__((address_space(3))) void*)(l), 16, 0, 0)
#define GLOAD_LDS4(g, l) \
    __builtin_amdgcn_global_load_lds((const __attribute__((address_space(1))) void*)(g), \
                                     (__attribute__((address_space(3))) void*)(l), 4, 0, 0)

// ---------------- prep: codebook -> f16 hi/lo split in FRAGMENT ORDER + (-0.5*|e|^2) ----
// Fragment slot for code k: gs = k>>4 (global step 0..63), l15 = k&15;
// slot = gs*64 + l4*16 + l15 (8 halves = 16 B per slot). Lane-linear for main.
__global__ __launch_bounds__(64) void vq_prep(
    const float* __restrict__ cb, float* __restrict__ nhb,
    _Float16* __restrict__ Eh, _Float16* __restrict__ El)
{
    const int k = blockIdx.x * 64 + threadIdx.x;   // code id
    const float4* e4 = reinterpret_cast<const float4*>(cb) + (size_t)k * 8;
    float v[DIM];
    float4 t[8];
#pragma unroll
    for (int j = 0; j < 8; ++j) t[j] = e4[j];
#pragma unroll
    for (int j = 0; j < 8; ++j) {
        v[4 * j + 0] = t[j].x; v[4 * j + 1] = t[j].y;
        v[4 * j + 2] = t[j].z; v[4 * j + 3] = t[j].w;
    }
    float e2 = 0.0f;
#pragma unroll
    for (int i = 0; i < DIM; ++i) e2 = fmaf(v[i], v[i], e2);   // sequential: matches rescore
    nhb[k] = -0.5f * e2;

    const int gs = k >> 4, l15 = k & 15;
#pragma unroll
    for (int l4 = 0; l4 < 4; ++l4) {
        half8 h, lo;
#pragma unroll
        for (int j = 0; j < 8; ++j) {
            float x = v[l4 * 8 + j];
            _Float16 hh = (_Float16)x;
            h[j]  = hh;
            lo[j] = (_Float16)(x - (float)hh);
        }
        const int slot = gs * 64 + l4 * 16 + l15;
        *reinterpret_cast<half8*>(Eh + (size_t)slot * 8) = h;
        *reinterpret_cast<half8*>(El + (size_t)slot * 8) = lo;
    }
}

// ---------------- main: whole-codebook-resident MFMA argmax + fused exact rescore ------
// 256 blocks x 1024 thr (16 waves); wave owns 32 tokens (m=2); ONE stage + ONE barrier,
// then a barrier-free sweep over all 1024 codes. LDS 137 KB -> 1 block/CU.
__global__ __launch_bounds__(1024) void vq_main(
    const float* __restrict__ w, const float* __restrict__ c,
    const float* __restrict__ nhb, const _Float16* __restrict__ Eh,
    const _Float16* __restrict__ El, const float* __restrict__ cb,
    int* __restrict__ out)
{
    __shared__ _Float16 sEh[4096 * 8];   // 64 KB: [gs(64)][lane(64)][8 halves]
    __shared__ _Float16 sEl[4096 * 8];   // 64 KB
    __shared__ float    snh[NCODE];      // 4 KB
    __shared__ int      sOut[512];       // 2 KB

    const int tid  = threadIdx.x;
    const int lane = tid & 63;
    const int wid  = tid >> 6;                      // 0..15
    const int tokw = blockIdx.x * 512 + wid * 32;   // 32 tokens per wave
    const int l15  = lane & 15;
    const int l4   = lane >> 4;

    // A fragments: 2 tiles of 16 tokens. A[row=l15][k=l4*8+j]; exact x = xh + xl
    half8 xh[2], xl[2];
#pragma unroll
    for (int m = 0; m < 2; ++m) {
        const int token = tokw + m * 16 + l15;
        const float4* pw = reinterpret_cast<const float4*>(w + (size_t)token * DIM + l4 * 8);
        const float4* pc = reinterpret_cast<const float4*>(c + (size_t)token * DIM + l4 * 8);
        float4 a0 = pw[0], a1 = pw[1], b0 = pc[0], b1 = pc[1];
        float xs[8] = {a0.x - b0.x, a0.y - b0.y, a0.z - b0.z, a0.w - b0.w,
                       a1.x - b1.x, a1.y - b1.y, a1.z - b1.z, a1.w - b1.w};
#pragma unroll
        for (int j = 0; j < 8; ++j) {
            _Float16 h = (_Float16)xs[j];
            xh[m][j] = h;
            xl[m][j] = (_Float16)(xs[j] - (float)h);
        }
    }

    // ---- stage ENTIRE codebook (hi+lo, 128 KB) + norms (4 KB), all-linear async
    {
#pragma unroll
        for (int r = 0; r < 4; ++r) {
            const int slot = r * 1024 + wid * 64;   // wave-uniform base
            GLOAD_LDS16(Eh + (size_t)(slot + lane) * 8, sEh + (size_t)slot * 8);
            GLOAD_LDS16(El + (size_t)(slot + lane) * 8, sEl + (size_t)slot * 8);
        }
        GLOAD_LDS4(nhb + wid * 64 + lane, snh + wid * 64);
    }
    __syncthreads();   // the ONLY barrier: codebook visible to all waves

    const float NEGINF = __uint_as_float(0xFF800000u);
    float best[8], second[8];
#pragma unroll
    for (int q = 0; q < 8; ++q) { best[q] = NEGINF; second[q] = NEGINF; }

    // 64 steps of 16 codes, in pairs (med3 second-tracking) -- R12's proven body
#pragma unroll 4
    for (int sp = 0; sp < 32; ++sp) {
        const int sA = 2 * sp, sB = 2 * sp + 1;
        const half8 ehA = *reinterpret_cast<const half8*>(sEh + (size_t)(sA * 64 + lane) * 8);
        const half8 elA = *reinterpret_cast<const half8*>(sEl + (size_t)(sA * 64 + lane) * 8);
        const half8 ehB = *reinterpret_cast<const half8*>(sEh + (size_t)(sB * 64 + lane) * 8);
        const half8 elB = *reinterpret_cast<const half8*>(sEl + (size_t)(sB * 64 + lane) * 8);
        const float nhA = snh[sA * 16 + l15];
        const float nhB = snh[sB * 16 + l15];
        const unsigned ixA = 1023u - (unsigned)(sA * 16 + l15);
        const unsigned ixB = ixA - 16u;
        const floatx4 nA = {nhA, nhA, nhA, nhA};
        const floatx4 nB = {nhB, nhB, nhB, nhB};
#pragma unroll
        for (int m = 0; m < 2; ++m) {
            floatx4 aA = __builtin_amdgcn_mfma_f32_16x16x32_f16(xh[m], ehA, nA, 0, 0, 0);
            aA = __builtin_amdgcn_mfma_f32_16x16x32_f16(xl[m], ehA, aA, 0, 0, 0);
            aA = __builtin_amdgcn_mfma_f32_16x16x32_f16(xh[m], elA, aA, 0, 0, 0);
            floatx4 aB = __builtin_amdgcn_mfma_f32_16x16x32_f16(xh[m], ehB, nB, 0, 0, 0);
            aB = __builtin_amdgcn_mfma_f32_16x16x32_f16(xl[m], ehB, aB, 0, 0, 0);
            aB = __builtin_amdgcn_mfma_f32_16x16x32_f16(xh[m], elB, aB, 0, 0, 0);
#pragma unroll
            for (int r = 0; r < 4; ++r) {
                const int q = m * 4 + r;
                float pA = __uint_as_float((__float_as_uint(aA[r]) & 0xFFFFFC00u) | ixA);
                float pB = __uint_as_float((__float_as_uint(aB[r]) & 0xFFFFFC00u) | ixB);
                second[q] = fmaxf(second[q], __builtin_amdgcn_fmed3f(pA, pB, best[q]));
                best[q]   = fmaxf(fmaxf(best[q], pA), pB);
            }
        }
    }

    // reduce across the 16 code-lanes (xor over lane bits 0..3)
#pragma unroll
    for (int sh = 1; sh < 16; sh <<= 1) {
#pragma unroll
        for (int q = 0; q < 8; ++q) {
            float bB = __shfl_xor(best[q], sh);
            float sB = __shfl_xor(second[q], sh);
            second[q] = fmaxf(fmaxf(second[q], sB), fminf(best[q], bB));
            best[q]   = fmaxf(best[q], bB);
        }
    }

    // stage per-token results (k | optional FLAGBIT) -- R12's proven threshold
    if (l15 == 0) {
#pragma unroll
        for (int m = 0; m < 2; ++m) {
#pragma unroll
            for (int r = 0; r < 4; ++r) {
                const int q = m * 4 + r;
                unsigned ub = __float_as_uint(best[q]);
                unsigned us = __float_as_uint(second[q]);
                float bv = __uint_as_float(ub & 0xFFFFFC00u);
                float sv = __uint_as_float(us & 0xFFFFFC00u);
                int eb = (int)((ub >> 23) & 255u);
                int es = (int)((us >> 23) & 255u);
                int em = eb > es ? eb : es;
                em = em > 12 ? em : 12;
                // flag threshold = 4 * packing granule + eps (covers split-f16 error)
                float thr = __uint_as_float((unsigned)(em - 11) << 23) + DELTA_EPS;
                int k = 1023 - (int)(ub & 1023u);
                sOut[wid * 32 + m * 16 + l4 * 4 + r] = ((bv - sv) < thr) ? (k | FLAGBIT) : k;
            }
        }
    }

    // lane i (<32) owns token tokw+i; rescore flagged tokens exactly (wave-cooperative).
    int myval = 0;
    if (lane < 32) myval = sOut[wid * 32 + lane];
    unsigned long long mask = __ballot(lane < 32 && (myval & FLAGBIT));
    while (mask) {
        const int src = __ffsll(mask) - 1;
        mask &= mask - 1;
        const int token = tokw + src;   // wave-uniform

        float x[DIM];
#pragma unroll
        for (int j = 0; j < 8; ++j) {
            float4 aw = reinterpret_cast<const float4*>(w + (size_t)token * DIM)[j];
            float4 ac = reinterpret_cast<const float4*>(c + (size_t)token * DIM)[j];
            x[4 * j + 0] = aw.x - ac.x; x[4 * j + 1] = aw.y - ac.y;
            x[4 * j + 2] = aw.z - ac.z; x[4 * j + 3] = aw.w - ac.w;
        }
        float x2 = 0.f;
#pragma unroll
        for (int i = 0; i < DIM; ++i) x2 = fmaf(x[i], x[i], x2);

        float dmin = INFINITY;
        int   kbest = 0;
#pragma unroll 2
        for (int i = 0; i < 16; ++i) {
            const int k = lane + 64 * i;           // ascending per lane
            const float4* e4 = reinterpret_cast<const float4*>(cb) + (size_t)k * 8;
            float4 ev[8];
#pragma unroll
            for (int j = 0; j < 8; ++j) ev[j] = e4[j];
            float dot = 0.f;
#pragma unroll
            for (int j = 0; j < 8; ++j) {          // sequential order: j*4+0..3
                dot = fmaf(x[4 * j + 0], ev[j].x, dot);
                dot = fmaf(x[4 * j + 1], ev[j].y, dot);
                dot = fmaf(x[4 * j + 2], ev[j].z, dot);
                dot = fmaf(x[4 * j + 3], ev[j].w, dot);
            }
            float e2 = -2.0f * nhb[k];             // bit-exact |e|^2 (seq-fma in prep)
            float dd = fmaf(-2.0f, dot, x2) + e2;
            if (dd < dmin) { dmin = dd; kbest = k; }
        }
#pragma unroll
        for (int sh = 1; sh < 64; sh <<= 1) {
            float dB = __shfl_xor(dmin, sh);
            int   iB = __shfl_xor(kbest, sh);
            bool take = (dB < dmin) || (dB == dmin && iB < kbest);
            dmin = take ? dB : dmin;
            kbest = take ? iB : kbest;
        }
        if (lane == src) myval = kbest;   // exact index, flag cleared
    }
    if (lane < 32) out[tokw + lane] = myval;   // coalesced 128 B per wave
}

extern "C" void kernel_launch(void* const* d_in, const int* in_sizes, int n_in,
                              void* d_out, int out_size, void* d_ws, size_t ws_size,
                              hipStream_t stream) {
    const float* w  = (const float*)d_in[0];   // weights   [4194304]
    const float* c  = (const float*)d_in[1];   // condition [1,32,131072] flat
    const float* cb = (const float*)d_in[2];   // codebook  [1024,32]
    int* out = (int*)d_out;                    // int32 indices [131072]

    char* wsb = (char*)d_ws;
    float*    nhb = (float*)wsb;                       // 4 KB
    _Float16* Eh  = (_Float16*)(wsb + 4096);           // 64 KB (fragment-ordered)
    _Float16* El  = (_Float16*)(wsb + 4096 + 65536);   // 64 KB (fragment-ordered)

    vq_prep<<<NCODE / 64, 64, 0, stream>>>(cb, nhb, Eh, El);
    vq_main<<<NTOK / 512, 1024, 0, stream>>>(w, c, nhb, Eh, El, cb, out);
}